// Round 1
// baseline (1760.898 us; speedup 1.0000x reference)
//
#include <hip/hip_runtime.h>

// Sizes (fixed for this problem)
#define T_TOK 1024
#define H_DIM 2048
#define E_NUM 32
#define I_DIM 1024
#define IS_DIM 2048

typedef float  f32x4 __attribute__((ext_vector_type(4)));
typedef short  s16x8 __attribute__((ext_vector_type(8)));
typedef unsigned short u16x4 __attribute__((ext_vector_type(4)));
typedef unsigned short u16x8 __attribute__((ext_vector_type(8)));

__device__ __forceinline__ unsigned short f2bf(float f) {
    unsigned u = __builtin_bit_cast(unsigned, f);
    u = (u + 0x7fffu + ((u >> 16) & 1u)) >> 16;
    return (unsigned short)u;
}

// ---------------------------------------------------------------------------
// Routing: one wave per token. Computes logits (x @ gate_w), sigmoid,
// grouped top-k (DeepSeek-V3 style), writes top-8 (idx, weight*2.5/sum).
// ---------------------------------------------------------------------------
__global__ __launch_bounds__(64) void route_k(
    const float* __restrict__ x, const float* __restrict__ gw,
    const float* __restrict__ bias, int* __restrict__ tidx,
    float* __restrict__ tw)
{
    const int t = blockIdx.x;
    const int lane = threadIdx.x;
    __shared__ float xs[H_DIM];
    __shared__ float sfc[E_NUM];
    __shared__ float sc[E_NUM];

    // stage x row
    for (int i = lane; i < H_DIM / 4; i += 64)
        *(f32x4*)&xs[i * 4] = *(const f32x4*)(x + (size_t)t * H_DIM + i * 4);
    __syncthreads();

    const int e = lane & 31;
    const int half = lane >> 5;
    float acc = 0.f;
    const float* gcol = gw + e;
    const int h0 = half * (H_DIM / 2);
    for (int h = h0; h < h0 + H_DIM / 2; ++h)
        acc += xs[h] * gcol[(size_t)h * E_NUM];
    acc += __shfl_xor(acc, 32);
    if (lane < 32) {
        float s = 1.f / (1.f + expf(-acc));
        sc[e] = s;
        sfc[e] = s + bias[e];
    }
    __syncthreads();

    if (lane == 0) {
        // group scores = sum of top-2 biased scores within each group of 8
        float gs[4];
        for (int gg = 0; gg < 4; ++gg) {
            float m1 = -1e30f, m2 = -1e30f;
            for (int j = 0; j < 8; ++j) {
                float v = sfc[gg * 8 + j];
                if (v > m1) { m2 = m1; m1 = v; }
                else if (v > m2) { m2 = v; }
            }
            gs[gg] = m1 + m2;
        }
        // top-2 groups (strict >, ties -> lower index, matches lax.top_k)
        int g1 = 0;
        for (int gg = 1; gg < 4; ++gg) if (gs[gg] > gs[g1]) g1 = gg;
        int g2 = (g1 == 0) ? 1 : 0;
        for (int gg = 0; gg < 4; ++gg)
            if (gg != g1 && gs[gg] > gs[g2]) g2 = gg;

        unsigned allow = (0xFFu << (g1 * 8)) | (0xFFu << (g2 * 8));
        unsigned taken = 0u;
        int   isel[8];
        float wsel[8];
        float wsum = 0.f;
        for (int k = 0; k < 8; ++k) {
            int best = 0; float bv = -1e30f;
            for (int e2 = 0; e2 < 32; ++e2) {
                if (((allow >> e2) & 1u) && !((taken >> e2) & 1u)) {
                    float v = sfc[e2];
                    if (v > bv) { bv = v; best = e2; }
                }
            }
            taken |= 1u << best;
            isel[k] = best;
            wsel[k] = sc[best];   // unbiased sigmoid score
            wsum += sc[best];
        }
        const float f = 2.5f / wsum;
        for (int k = 0; k < 8; ++k) {
            tidx[t * 8 + k] = isel[k];
            tw[t * 8 + k] = wsel[k] * f;
        }
    }
}

// ---------------------------------------------------------------------------
// Build per-expert token lists (deterministic order: ascending token id).
// One wave per expert.
// ---------------------------------------------------------------------------
__global__ __launch_bounds__(64) void build_k(
    const int* __restrict__ tidx, const float* __restrict__ tw,
    int* __restrict__ ltok, float* __restrict__ lw, int* __restrict__ counts)
{
    const int e = blockIdx.x;
    const int lane = threadIdx.x;
    int cnt = 0;
    for (int t0 = 0; t0 < T_TOK; t0 += 64) {
        const int t = t0 + lane;
        int sel = 0; float w = 0.f;
        #pragma unroll
        for (int k = 0; k < 8; ++k) {
            if (tidx[t * 8 + k] == e) { sel = 1; w = tw[t * 8 + k]; }
        }
        unsigned long long m = __ballot(sel);
        int pos = __popcll(m & ((1ull << lane) - 1ull));
        if (sel) {
            ltok[e * T_TOK + cnt + pos] = t;
            lw[e * T_TOK + cnt + pos] = w;
        }
        cnt += __popcll(m);
    }
    if (lane == 0) counts[e] = cnt;
}

__global__ void prefix_k(const int* __restrict__ counts, int* __restrict__ offsets)
{
    if (threadIdx.x == 0) {
        int off = 0;
        for (int e = 0; e < E_NUM; ++e) { offsets[e] = off; off += counts[e]; }
    }
}

// ---------------------------------------------------------------------------
// GEMM template: 64x64 tile, BK=64, 4 waves, mfma_f32_16x16x32_bf16.
// DUAL:   two B matrices (gate+up) fused with SiLU -> bf16 act store
// EXPERT: blockIdx.z selects expert; M = counts[e]
// ABF16:  A is bf16 (activation buffer), else fp32 (converted on stage)
// ATOMIC: epilogue does atomicAdd(out[token]) scaled by per-row weight
// ---------------------------------------------------------------------------
template<int DUAL, int EXPERT, int ABF16, int ATOMIC>
__global__ __launch_bounds__(256) void gemm_k(
    const void* __restrict__ Av, const float* __restrict__ B1g,
    const float* __restrict__ B2g, void* __restrict__ outv,
    const int* __restrict__ counts, const int* __restrict__ offsets,
    const int* __restrict__ ltok, const float* __restrict__ lw,
    int M, int N, int K)
{
    const int e = blockIdx.z;
    int Mloc = M;
    if (EXPERT) Mloc = counts[e];
    const int row0 = blockIdx.x * 64;
    if (row0 >= Mloc) return;
    const int col0 = blockIdx.y * 64;

    const float* B1 = B1g;
    const float* B2 = B2g;
    if (EXPERT) {
        size_t eo = (size_t)e * K * N;
        B1 += eo;
        if (DUAL) B2 += eo;
    }

    __shared__ unsigned short lA[64][72];
    __shared__ unsigned short lB[(DUAL ? 2 : 1)][64][72];

    const int tid = threadIdx.x;
    const int lane = tid & 63;
    const int wv = tid >> 6;
    const int wm = wv >> 1, wn = wv & 1;

    // Precompute A row pointers for the staging loop
    const float* arf[4];
    const unsigned short* arb[2];
    if (ABF16) {
        const unsigned short* A = (const unsigned short*)Av;
        const int rb = EXPERT ? offsets[e] : 0;
        #pragma unroll
        for (int i = 0; i < 2; ++i) {
            int r = ((i << 8) + tid) >> 3;
            int rr = row0 + r; if (rr >= Mloc) rr = Mloc - 1;
            arb[i] = A + (size_t)(rb + rr) * K;
        }
    } else {
        const float* A = (const float*)Av;
        #pragma unroll
        for (int i = 0; i < 4; ++i) {
            int r = ((i << 8) + tid) >> 4;
            int rr = row0 + r; if (rr >= Mloc) rr = Mloc - 1;
            int grow = EXPERT ? ltok[e * T_TOK + rr] : rr;
            arf[i] = A + (size_t)grow * K;
        }
    }
    const int bn = tid & 63, kq = tid >> 6;

    f32x4 acc1[2][2], acc2[2][2];
    #pragma unroll
    for (int a = 0; a < 2; ++a)
        #pragma unroll
        for (int b = 0; b < 2; ++b) {
            acc1[a][b] = f32x4{0.f, 0.f, 0.f, 0.f};
            acc2[a][b] = f32x4{0.f, 0.f, 0.f, 0.f};
        }

    const int nK = K >> 6;
    for (int kt = 0; kt < nK; ++kt) {
        const int k0 = kt << 6;
        // ---- stage A ----
        if (ABF16) {
            #pragma unroll
            for (int i = 0; i < 2; ++i) {
                int idx = (i << 8) + tid;
                int r = idx >> 3, c = idx & 7;
                u16x8 v = *(const u16x8*)(arb[i] + k0 + c * 8);
                *(u16x8*)&lA[r][c * 8] = v;
            }
        } else {
            #pragma unroll
            for (int i = 0; i < 4; ++i) {
                int idx = (i << 8) + tid;
                int r = idx >> 4, kc = idx & 15;
                f32x4 v = *(const f32x4*)(arf[i] + k0 + kc * 4);
                u16x4 h = { f2bf(v[0]), f2bf(v[1]), f2bf(v[2]), f2bf(v[3]) };
                *(u16x4*)&lA[r][kc * 4] = h;
            }
        }
        // ---- stage B (transpose to [n][k] in LDS) ----
        {
            const float* bp = B1 + (size_t)(k0 + kq * 16) * N + col0 + bn;
            float v[16];
            #pragma unroll
            for (int j = 0; j < 16; ++j) v[j] = bp[(size_t)j * N];
            #pragma unroll
            for (int c = 0; c < 4; ++c) {
                u16x4 h = { f2bf(v[c*4+0]), f2bf(v[c*4+1]), f2bf(v[c*4+2]), f2bf(v[c*4+3]) };
                *(u16x4*)&lB[0][bn][kq * 16 + c * 4] = h;
            }
            if (DUAL) {
                const float* bp2 = B2 + (size_t)(k0 + kq * 16) * N + col0 + bn;
                #pragma unroll
                for (int j = 0; j < 16; ++j) v[j] = bp2[(size_t)j * N];
                #pragma unroll
                for (int c = 0; c < 4; ++c) {
                    u16x4 h = { f2bf(v[c*4+0]), f2bf(v[c*4+1]), f2bf(v[c*4+2]), f2bf(v[c*4+3]) };
                    *(u16x4*)&lB[DUAL][bn][kq * 16 + c * 4] = h;
                }
            }
        }
        __syncthreads();
        // ---- MFMA ----
        #pragma unroll
        for (int g = 0; g < 2; ++g) {
            const int koff = g * 32 + (lane >> 4) * 8;
            s16x8 af[2], b1f[2], b2f[2];
            #pragma unroll
            for (int fm = 0; fm < 2; ++fm)
                af[fm] = *(const s16x8*)&lA[wm * 32 + fm * 16 + (lane & 15)][koff];
            #pragma unroll
            for (int fn = 0; fn < 2; ++fn) {
                b1f[fn] = *(const s16x8*)&lB[0][wn * 32 + fn * 16 + (lane & 15)][koff];
                if (DUAL) b2f[fn] = *(const s16x8*)&lB[DUAL][wn * 32 + fn * 16 + (lane & 15)][koff];
            }
            #pragma unroll
            for (int fm = 0; fm < 2; ++fm)
                #pragma unroll
                for (int fn = 0; fn < 2; ++fn) {
                    acc1[fm][fn] = __builtin_amdgcn_mfma_f32_16x16x32_bf16(
                        af[fm], b1f[fn], acc1[fm][fn], 0, 0, 0);
                    if (DUAL)
                        acc2[fm][fn] = __builtin_amdgcn_mfma_f32_16x16x32_bf16(
                            af[fm], b2f[fn], acc2[fm][fn], 0, 0, 0);
                }
        }
        __syncthreads();
    }

    // ---- epilogue ----
    const int lr = wm * 32 + ((lane >> 4) << 2);
    const int lc = wn * 32 + (lane & 15);
    if (DUAL) {
        unsigned short* outp = (unsigned short*)outv;
        const int rb = EXPERT ? offsets[e] : 0;
        #pragma unroll
        for (int fm = 0; fm < 2; ++fm)
            #pragma unroll
            for (int fn = 0; fn < 2; ++fn)
                #pragma unroll
                for (int j = 0; j < 4; ++j) {
                    int r = lr + fm * 16 + j;
                    if (row0 + r < Mloc) {
                        int cc = col0 + lc + fn * 16;
                        float gv = acc1[fm][fn][j];
                        float uv = acc2[fm][fn][j];
                        float a = gv / (1.f + expf(-gv)) * uv;  // silu(g)*u
                        outp[(size_t)(rb + row0 + r) * N + cc] = f2bf(a);
                    }
                }
    } else if (ATOMIC) {
        float* outp = (float*)outv;
        #pragma unroll
        for (int fm = 0; fm < 2; ++fm)
            #pragma unroll
            for (int fn = 0; fn < 2; ++fn)
                #pragma unroll
                for (int j = 0; j < 4; ++j) {
                    int r = lr + fm * 16 + j;
                    if (row0 + r < Mloc) {
                        int tok = ltok[e * T_TOK + row0 + r];
                        float wr = lw[e * T_TOK + row0 + r];
                        int cc = col0 + lc + fn * 16;
                        atomicAdd(outp + (size_t)tok * N + cc, acc1[fm][fn][j] * wr);
                    }
                }
    } else {
        float* outp = (float*)outv;
        #pragma unroll
        for (int fm = 0; fm < 2; ++fm)
            #pragma unroll
            for (int fn = 0; fn < 2; ++fn)
                #pragma unroll
                for (int j = 0; j < 4; ++j) {
                    int r = lr + fm * 16 + j;
                    int cc = col0 + lc + fn * 16;
                    outp[(size_t)(row0 + r) * N + cc] = acc1[fm][fn][j];
                }
    }
}

// ---------------------------------------------------------------------------
extern "C" void kernel_launch(void* const* d_in, const int* in_sizes, int n_in,
                              void* d_out, int out_size, void* d_ws, size_t ws_size,
                              hipStream_t stream) {
    const float* x       = (const float*)d_in[0];
    const float* gate_w  = (const float*)d_in[1];
    const float* bias    = (const float*)d_in[2];
    const float* w_gate  = (const float*)d_in[3];
    const float* w_up    = (const float*)d_in[4];
    const float* w_down  = (const float*)d_in[5];
    const float* sw_gate = (const float*)d_in[6];
    const float* sw_up   = (const float*)d_in[7];
    const float* sw_down = (const float*)d_in[8];
    float* out = (float*)d_out;

    char* ws = (char*)d_ws;
    int*   topk_idx = (int*)ws;                                   // 32 KB
    float* topk_w   = (float*)(ws + 32768);                       // 32 KB
    int*   counts   = (int*)(ws + 65536);                         // 128 B
    int*   offsets  = (int*)(ws + 65536 + 128);                   // 128 B
    int*   ltok     = (int*)(ws + 65536 + 256);                   // 128 KB
    float* lw       = (float*)(ws + 65536 + 256 + 131072);        // 128 KB
    unsigned short* act_s = (unsigned short*)(ws + 65536 + 256 + 262144);  // 4 MB
    unsigned short* act_r = act_s + (size_t)T_TOK * IS_DIM;               // 16 MB

    route_k<<<T_TOK, 64, 0, stream>>>(x, gate_w, bias, topk_idx, topk_w);
    build_k<<<E_NUM, 64, 0, stream>>>(topk_idx, topk_w, ltok, lw, counts);
    prefix_k<<<1, 64, 0, stream>>>(counts, offsets);

    // shared gate/up:  [1024,2048] @ [2048,2048] x2, SiLU-fused -> act_s (bf16)
    gemm_k<1,0,0,0><<<dim3(16, 32, 1), 256, 0, stream>>>(
        x, sw_gate, sw_up, act_s, nullptr, nullptr, nullptr, nullptr,
        T_TOK, IS_DIM, H_DIM);
    // routed gate/up: gathered rows, per expert -> act_r (bf16)
    gemm_k<1,1,0,0><<<dim3(16, 16, 32), 256, 0, stream>>>(
        x, w_gate, w_up, act_r, counts, offsets, ltok, lw,
        T_TOK, I_DIM, H_DIM);
    // shared down: act_s @ sw_down -> out (plain store, initializes out)
    gemm_k<0,0,1,0><<<dim3(16, 32, 1), 256, 0, stream>>>(
        act_s, sw_down, nullptr, out, nullptr, nullptr, nullptr, nullptr,
        T_TOK, H_DIM, IS_DIM);
    // routed down: act_r @ w_down, scaled atomicAdd into out
    gemm_k<0,1,1,1><<<dim3(16, 32, 32), 256, 0, stream>>>(
        act_r, w_down, nullptr, out, counts, offsets, ltok, lw,
        T_TOK, H_DIM, I_DIM);
}

// Round 2
// 1685.778 us; speedup vs baseline: 1.0446x; 1.0446x over previous
//
#include <hip/hip_runtime.h>

// Sizes (fixed for this problem)
#define T_TOK 1024
#define H_DIM 2048
#define E_NUM 32
#define I_DIM 1024
#define IS_DIM 2048

typedef float  f32x4 __attribute__((ext_vector_type(4)));
typedef short  s16x8 __attribute__((ext_vector_type(8)));
typedef unsigned short u16x4 __attribute__((ext_vector_type(4)));
typedef unsigned short u16x8 __attribute__((ext_vector_type(8)));

__device__ __forceinline__ unsigned short f2bf(float f) {
    unsigned u = __builtin_bit_cast(unsigned, f);
    u = (u + 0x7fffu + ((u >> 16) & 1u)) >> 16;
    return (unsigned short)u;
}

// ---------------------------------------------------------------------------
// Routing: one wave per token.
// ---------------------------------------------------------------------------
__global__ __launch_bounds__(64) void route_k(
    const float* __restrict__ x, const float* __restrict__ gw,
    const float* __restrict__ bias, int* __restrict__ tidx,
    float* __restrict__ tw)
{
    const int t = blockIdx.x;
    const int lane = threadIdx.x;
    __shared__ float xs[H_DIM];
    __shared__ float sfc[E_NUM];
    __shared__ float sc[E_NUM];

    for (int i = lane; i < H_DIM / 4; i += 64)
        *(f32x4*)&xs[i * 4] = *(const f32x4*)(x + (size_t)t * H_DIM + i * 4);
    __syncthreads();

    const int e = lane & 31;
    const int half = lane >> 5;
    float acc = 0.f;
    const float* gcol = gw + e;
    const int h0 = half * (H_DIM / 2);
    for (int h = h0; h < h0 + H_DIM / 2; ++h)
        acc += xs[h] * gcol[(size_t)h * E_NUM];
    acc += __shfl_xor(acc, 32);
    if (lane < 32) {
        float s = 1.f / (1.f + expf(-acc));
        sc[e] = s;
        sfc[e] = s + bias[e];
    }
    __syncthreads();

    if (lane == 0) {
        float gs[4];
        for (int gg = 0; gg < 4; ++gg) {
            float m1 = -1e30f, m2 = -1e30f;
            for (int j = 0; j < 8; ++j) {
                float v = sfc[gg * 8 + j];
                if (v > m1) { m2 = m1; m1 = v; }
                else if (v > m2) { m2 = v; }
            }
            gs[gg] = m1 + m2;
        }
        int g1 = 0;
        for (int gg = 1; gg < 4; ++gg) if (gs[gg] > gs[g1]) g1 = gg;
        int g2 = (g1 == 0) ? 1 : 0;
        for (int gg = 0; gg < 4; ++gg)
            if (gg != g1 && gs[gg] > gs[g2]) g2 = gg;

        unsigned allow = (0xFFu << (g1 * 8)) | (0xFFu << (g2 * 8));
        unsigned taken = 0u;
        int   isel[8];
        float wsel[8];
        float wsum = 0.f;
        for (int k = 0; k < 8; ++k) {
            int best = 0; float bv = -1e30f;
            for (int e2 = 0; e2 < 32; ++e2) {
                if (((allow >> e2) & 1u) && !((taken >> e2) & 1u)) {
                    float v = sfc[e2];
                    if (v > bv) { bv = v; best = e2; }
                }
            }
            taken |= 1u << best;
            isel[k] = best;
            wsel[k] = sc[best];
            wsum += sc[best];
        }
        const float f = 2.5f / wsum;
        for (int k = 0; k < 8; ++k) {
            tidx[t * 8 + k] = isel[k];
            tw[t * 8 + k] = wsel[k] * f;
        }
    }
}

// ---------------------------------------------------------------------------
// Build per-expert token lists (ascending token id). One wave per expert.
// ---------------------------------------------------------------------------
__global__ __launch_bounds__(64) void build_k(
    const int* __restrict__ tidx, const float* __restrict__ tw,
    int* __restrict__ ltok, float* __restrict__ lw, int* __restrict__ counts)
{
    const int e = blockIdx.x;
    const int lane = threadIdx.x;
    int cnt = 0;
    for (int t0 = 0; t0 < T_TOK; t0 += 64) {
        const int t = t0 + lane;
        int sel = 0; float w = 0.f;
        #pragma unroll
        for (int k = 0; k < 8; ++k) {
            if (tidx[t * 8 + k] == e) { sel = 1; w = tw[t * 8 + k]; }
        }
        unsigned long long m = __ballot(sel);
        int pos = __popcll(m & ((1ull << lane) - 1ull));
        if (sel) {
            ltok[e * T_TOK + cnt + pos] = t;
            lw[e * T_TOK + cnt + pos] = w;
        }
        cnt += __popcll(m);
    }
    if (lane == 0) counts[e] = cnt;
}

__global__ void prefix_k(const int* __restrict__ counts, int* __restrict__ offsets)
{
    if (threadIdx.x == 0) {
        int off = 0;
        for (int e = 0; e < E_NUM; ++e) { offsets[e] = off; off += counts[e]; }
    }
}

// ---------------------------------------------------------------------------
// GEMM: 256x64 tile, BK=64, 512 threads (8 waves, 4Mx2N, wave tile 64x32),
// mfma_f32_16x16x32_bf16, register-prefetch of next K-tile (T14-lite).
// DUAL:   two B matrices (gate+up), SiLU fused, bf16 act store
// EXPERT: blockIdx.z = expert, M = counts[e]
// ABF16:  A is bf16 activation buffer (else fp32, converted while staging)
// ATOMIC: scaled atomicAdd(out[token])
// ---------------------------------------------------------------------------
template<int DUAL, int EXPERT, int ABF16, int ATOMIC>
__global__ __launch_bounds__(512) void gemm_k(
    const void* __restrict__ Av, const float* __restrict__ B1g,
    const float* __restrict__ B2g, void* __restrict__ outv,
    const int* __restrict__ counts, const int* __restrict__ offsets,
    const int* __restrict__ ltok, const float* __restrict__ lw,
    int M, int N, int K)
{
    const int e = blockIdx.z;
    int Mloc = M;
    if (EXPERT) Mloc = counts[e];
    const int row0 = blockIdx.x * 256;
    if (row0 >= Mloc) return;
    const int col0 = blockIdx.y * 64;

    const float* B1 = B1g;
    const float* B2 = B2g;
    if (EXPERT) {
        size_t eo = (size_t)e * K * N;
        B1 += eo;
        if (DUAL) B2 += eo;
    }

    __shared__ unsigned short lA[256][72];
    __shared__ unsigned short lB[(DUAL ? 2 : 1)][64][72];

    const int tid = threadIdx.x;
    const int lane = tid & 63;
    const int wv = tid >> 6;       // 0..7
    const int wm = wv >> 1;        // 0..3 (64-row stripes)
    const int wn = wv & 1;         // 0..1 (32-col stripes)

    // ---- A row pointers (fixed per thread) ----
    const float* arf[8];
    const unsigned short* arb[4];
    if (ABF16) {
        const unsigned short* A = (const unsigned short*)Av;
        const int rb = EXPERT ? offsets[e] : 0;
        #pragma unroll
        for (int i = 0; i < 4; ++i) {
            int rr = row0 + i * 64 + (tid >> 3);
            if (rr >= Mloc) rr = Mloc - 1;
            arb[i] = A + (size_t)(rb + rr) * K + (tid & 7) * 8;
        }
    } else {
        const float* A = (const float*)Av;
        #pragma unroll
        for (int i = 0; i < 8; ++i) {
            int rr = row0 + i * 32 + (tid >> 4);
            if (rr >= Mloc) rr = Mloc - 1;
            int grow = EXPERT ? ltok[e * T_TOK + rr] : rr;
            arf[i] = A + (size_t)grow * K + (tid & 15) * 4;
        }
    }
    // ---- B pointers ----
    const int nq = tid & 15;          // 4-col group within 64-col panel
    const int kb = tid >> 4;          // 0..31 (k row within half K-tile)
    const float* bp1 = B1 + col0 + nq * 4;
    const float* bp2 = DUAL ? (B2 + col0 + nq * 4) : bp1;

    f32x4 acc1[4][2], acc2[4][2];
    #pragma unroll
    for (int a = 0; a < 4; ++a)
        #pragma unroll
        for (int b = 0; b < 2; ++b) {
            acc1[a][b] = f32x4{0.f, 0.f, 0.f, 0.f};
            acc2[a][b] = f32x4{0.f, 0.f, 0.f, 0.f};
        }

    f32x4 pa[8];
    u16x8 pab[4];
    f32x4 pb[4];

    auto loadT = [&](int k0) {
        if (ABF16) {
            #pragma unroll
            for (int i = 0; i < 4; ++i) pab[i] = *(const u16x8*)(arb[i] + k0);
        } else {
            #pragma unroll
            for (int i = 0; i < 8; ++i) pa[i] = *(const f32x4*)(arf[i] + k0);
        }
        pb[0] = *(const f32x4*)(bp1 + (size_t)(k0 + kb) * N);
        pb[1] = *(const f32x4*)(bp1 + (size_t)(k0 + 32 + kb) * N);
        if (DUAL) {
            pb[2] = *(const f32x4*)(bp2 + (size_t)(k0 + kb) * N);
            pb[3] = *(const f32x4*)(bp2 + (size_t)(k0 + 32 + kb) * N);
        }
    };

    auto storeT = [&]() {
        if (ABF16) {
            #pragma unroll
            for (int i = 0; i < 4; ++i)
                *(u16x8*)&lA[i * 64 + (tid >> 3)][(tid & 7) * 8] = pab[i];
        } else {
            #pragma unroll
            for (int i = 0; i < 8; ++i) {
                u16x4 h = { f2bf(pa[i][0]), f2bf(pa[i][1]),
                            f2bf(pa[i][2]), f2bf(pa[i][3]) };
                *(u16x4*)&lA[i * 32 + (tid >> 4)][(tid & 15) * 4] = h;
            }
        }
        #pragma unroll
        for (int j = 0; j < 4; ++j) lB[0][nq * 4 + j][kb]      = f2bf(pb[0][j]);
        #pragma unroll
        for (int j = 0; j < 4; ++j) lB[0][nq * 4 + j][32 + kb] = f2bf(pb[1][j]);
        if (DUAL) {
            #pragma unroll
            for (int j = 0; j < 4; ++j) lB[1][nq * 4 + j][kb]      = f2bf(pb[2][j]);
            #pragma unroll
            for (int j = 0; j < 4; ++j) lB[1][nq * 4 + j][32 + kb] = f2bf(pb[3][j]);
        }
    };

    const int nK = K >> 6;
    loadT(0);
    for (int kt = 0; kt < nK; ++kt) {
        __syncthreads();                 // previous MFMA done with LDS
        storeT();
        __syncthreads();                 // tile visible
        if (kt + 1 < nK) loadT((kt + 1) << 6);   // prefetch flies during MFMA
        #pragma unroll
        for (int kg = 0; kg < 2; ++kg) {
            const int koff = kg * 32 + (lane >> 4) * 8;
            s16x8 af[4], b1f[2], b2f[2];
            #pragma unroll
            for (int fm = 0; fm < 4; ++fm)
                af[fm] = *(const s16x8*)&lA[wm * 64 + fm * 16 + (lane & 15)][koff];
            #pragma unroll
            for (int fn = 0; fn < 2; ++fn) {
                b1f[fn] = *(const s16x8*)&lB[0][wn * 32 + fn * 16 + (lane & 15)][koff];
                if (DUAL)
                    b2f[fn] = *(const s16x8*)&lB[1][wn * 32 + fn * 16 + (lane & 15)][koff];
            }
            #pragma unroll
            for (int fm = 0; fm < 4; ++fm)
                #pragma unroll
                for (int fn = 0; fn < 2; ++fn) {
                    acc1[fm][fn] = __builtin_amdgcn_mfma_f32_16x16x32_bf16(
                        af[fm], b1f[fn], acc1[fm][fn], 0, 0, 0);
                    if (DUAL)
                        acc2[fm][fn] = __builtin_amdgcn_mfma_f32_16x16x32_bf16(
                            af[fm], b2f[fn], acc2[fm][fn], 0, 0, 0);
                }
        }
    }

    // ---- epilogue ----
    const int fr = (lane >> 4) << 2;   // 0,4,8,12
    const int fc = lane & 15;
    if (DUAL) {
        unsigned short* outp = (unsigned short*)outv;
        const int rb = EXPERT ? offsets[e] : 0;
        #pragma unroll
        for (int fm = 0; fm < 4; ++fm)
            #pragma unroll
            for (int fn = 0; fn < 2; ++fn)
                #pragma unroll
                for (int j = 0; j < 4; ++j) {
                    int r = wm * 64 + fm * 16 + fr + j;
                    if (row0 + r < Mloc) {
                        int cc = col0 + wn * 32 + fn * 16 + fc;
                        float gv = acc1[fm][fn][j];
                        float uv = acc2[fm][fn][j];
                        float a = gv / (1.f + expf(-gv)) * uv;
                        outp[(size_t)(rb + row0 + r) * N + cc] = f2bf(a);
                    }
                }
    } else if (ATOMIC) {
        float* outp = (float*)outv;
        #pragma unroll
        for (int fm = 0; fm < 4; ++fm)
            #pragma unroll
            for (int fn = 0; fn < 2; ++fn)
                #pragma unroll
                for (int j = 0; j < 4; ++j) {
                    int r = wm * 64 + fm * 16 + fr + j;
                    if (row0 + r < Mloc) {
                        int tok = ltok[e * T_TOK + row0 + r];
                        float wr = lw[e * T_TOK + row0 + r];
                        int cc = col0 + wn * 32 + fn * 16 + fc;
                        atomicAdd(outp + (size_t)tok * N + cc, acc1[fm][fn][j] * wr);
                    }
                }
    } else {
        float* outp = (float*)outv;
        #pragma unroll
        for (int fm = 0; fm < 4; ++fm)
            #pragma unroll
            for (int fn = 0; fn < 2; ++fn)
                #pragma unroll
                for (int j = 0; j < 4; ++j) {
                    int r = wm * 64 + fm * 16 + fr + j;
                    if (row0 + r < Mloc) {
                        int cc = col0 + wn * 32 + fn * 16 + fc;
                        outp[(size_t)(row0 + r) * N + cc] = acc1[fm][fn][j];
                    }
                }
    }
}

// ---------------------------------------------------------------------------
extern "C" void kernel_launch(void* const* d_in, const int* in_sizes, int n_in,
                              void* d_out, int out_size, void* d_ws, size_t ws_size,
                              hipStream_t stream) {
    const float* x       = (const float*)d_in[0];
    const float* gate_w  = (const float*)d_in[1];
    const float* bias    = (const float*)d_in[2];
    const float* w_gate  = (const float*)d_in[3];
    const float* w_up    = (const float*)d_in[4];
    const float* w_down  = (const float*)d_in[5];
    const float* sw_gate = (const float*)d_in[6];
    const float* sw_up   = (const float*)d_in[7];
    const float* sw_down = (const float*)d_in[8];
    float* out = (float*)d_out;

    char* ws = (char*)d_ws;
    int*   topk_idx = (int*)ws;                                   // 32 KB
    float* topk_w   = (float*)(ws + 32768);                       // 32 KB
    int*   counts   = (int*)(ws + 65536);                         // 128 B
    int*   offsets  = (int*)(ws + 65536 + 128);                   // 128 B
    int*   ltok     = (int*)(ws + 65536 + 256);                   // 128 KB
    float* lw       = (float*)(ws + 65536 + 256 + 131072);        // 128 KB
    unsigned short* act_s = (unsigned short*)(ws + 65536 + 256 + 262144);  // 4 MB
    unsigned short* act_r = act_s + (size_t)T_TOK * IS_DIM;               // 16 MB

    route_k<<<T_TOK, 64, 0, stream>>>(x, gate_w, bias, topk_idx, topk_w);
    build_k<<<E_NUM, 64, 0, stream>>>(topk_idx, topk_w, ltok, lw, counts);
    prefix_k<<<1, 64, 0, stream>>>(counts, offsets);

    // shared gate/up -> act_s (bf16)
    gemm_k<1,0,0,0><<<dim3(4, 32, 1), 512, 0, stream>>>(
        x, sw_gate, sw_up, act_s, nullptr, nullptr, nullptr, nullptr,
        T_TOK, IS_DIM, H_DIM);
    // routed gate/up -> act_r (bf16)
    gemm_k<1,1,0,0><<<dim3(4, 16, 32), 512, 0, stream>>>(
        x, w_gate, w_up, act_r, counts, offsets, ltok, lw,
        T_TOK, I_DIM, H_DIM);
    // shared down -> out (plain store, initializes out)
    gemm_k<0,0,1,0><<<dim3(4, 32, 1), 512, 0, stream>>>(
        act_s, sw_down, nullptr, out, nullptr, nullptr, nullptr, nullptr,
        T_TOK, H_DIM, IS_DIM);
    // routed down -> out (scaled atomicAdd)
    gemm_k<0,1,1,1><<<dim3(4, 32, 32), 512, 0, stream>>>(
        act_r, w_down, nullptr, out, counts, offsets, ltok, lw,
        T_TOK, H_DIM, I_DIM);
}

// Round 3
// 1530.417 us; speedup vs baseline: 1.1506x; 1.1015x over previous
//
#include <hip/hip_runtime.h>

// Sizes (fixed for this problem)
#define T_TOK 1024
#define H_DIM 2048
#define E_NUM 32
#define I_DIM 1024
#define IS_DIM 2048

typedef float  f32x4 __attribute__((ext_vector_type(4)));
typedef short  s16x8 __attribute__((ext_vector_type(8)));
typedef unsigned short u16x2 __attribute__((ext_vector_type(2)));
typedef unsigned short u16x8 __attribute__((ext_vector_type(8)));

__device__ __forceinline__ unsigned short f2bf(float f) {
    unsigned u = __builtin_bit_cast(unsigned, f);
    u = (u + 0x7fffu + ((u >> 16) & 1u)) >> 16;
    return (unsigned short)u;
}

// ---------------------------------------------------------------------------
// Routing: one wave per token.
// ---------------------------------------------------------------------------
__global__ __launch_bounds__(64) void route_k(
    const float* __restrict__ x, const float* __restrict__ gw,
    const float* __restrict__ bias, int* __restrict__ tidx,
    float* __restrict__ tw)
{
    const int t = blockIdx.x;
    const int lane = threadIdx.x;
    __shared__ float xs[H_DIM];
    __shared__ float sfc[E_NUM];
    __shared__ float sc[E_NUM];

    for (int i = lane; i < H_DIM / 4; i += 64)
        *(f32x4*)&xs[i * 4] = *(const f32x4*)(x + (size_t)t * H_DIM + i * 4);
    __syncthreads();

    const int e = lane & 31;
    const int half = lane >> 5;
    float acc = 0.f;
    const float* gcol = gw + e;
    const int h0 = half * (H_DIM / 2);
    for (int h = h0; h < h0 + H_DIM / 2; ++h)
        acc += xs[h] * gcol[(size_t)h * E_NUM];
    acc += __shfl_xor(acc, 32);
    if (lane < 32) {
        float s = 1.f / (1.f + expf(-acc));
        sc[e] = s;
        sfc[e] = s + bias[e];
    }
    __syncthreads();

    if (lane == 0) {
        float gs[4];
        for (int gg = 0; gg < 4; ++gg) {
            float m1 = -1e30f, m2 = -1e30f;
            for (int j = 0; j < 8; ++j) {
                float v = sfc[gg * 8 + j];
                if (v > m1) { m2 = m1; m1 = v; }
                else if (v > m2) { m2 = v; }
            }
            gs[gg] = m1 + m2;
        }
        int g1 = 0;
        for (int gg = 1; gg < 4; ++gg) if (gs[gg] > gs[g1]) g1 = gg;
        int g2 = (g1 == 0) ? 1 : 0;
        for (int gg = 0; gg < 4; ++gg)
            if (gg != g1 && gs[gg] > gs[g2]) g2 = gg;

        unsigned allow = (0xFFu << (g1 * 8)) | (0xFFu << (g2 * 8));
        unsigned taken = 0u;
        int   isel[8];
        float wsel[8];
        float wsum = 0.f;
        for (int k = 0; k < 8; ++k) {
            int best = 0; float bv = -1e30f;
            for (int e2 = 0; e2 < 32; ++e2) {
                if (((allow >> e2) & 1u) && !((taken >> e2) & 1u)) {
                    float v = sfc[e2];
                    if (v > bv) { bv = v; best = e2; }
                }
            }
            taken |= 1u << best;
            isel[k] = best;
            wsel[k] = sc[best];
            wsum += sc[best];
        }
        const float f = 2.5f / wsum;
        for (int k = 0; k < 8; ++k) {
            tidx[t * 8 + k] = isel[k];
            tw[t * 8 + k] = wsel[k] * f;
        }
    }
}

// ---------------------------------------------------------------------------
// Build per-expert token lists (ascending token id). One wave per expert.
// ---------------------------------------------------------------------------
__global__ __launch_bounds__(64) void build_k(
    const int* __restrict__ tidx, const float* __restrict__ tw,
    int* __restrict__ ltok, float* __restrict__ lw, int* __restrict__ counts)
{
    const int e = blockIdx.x;
    const int lane = threadIdx.x;
    int cnt = 0;
    for (int t0 = 0; t0 < T_TOK; t0 += 64) {
        const int t = t0 + lane;
        int sel = 0; float w = 0.f;
        #pragma unroll
        for (int k = 0; k < 8; ++k) {
            if (tidx[t * 8 + k] == e) { sel = 1; w = tw[t * 8 + k]; }
        }
        unsigned long long m = __ballot(sel);
        int pos = __popcll(m & ((1ull << lane) - 1ull));
        if (sel) {
            ltok[e * T_TOK + cnt + pos] = t;
            lw[e * T_TOK + cnt + pos] = w;
        }
        cnt += __popcll(m);
    }
    if (lane == 0) counts[e] = cnt;
}

__global__ void prefix_k(const int* __restrict__ counts, int* __restrict__ offsets)
{
    if (threadIdx.x == 0) {
        int off = 0;
        for (int e = 0; e < E_NUM; ++e) { offsets[e] = off; off += counts[e]; }
    }
}

// ---------------------------------------------------------------------------
// GEMM: BMx64 tile, BK=32, 512 threads (8 waves, 4Mx2N), double-buffered LDS,
// one barrier per K-tile, register prefetch one tile ahead.
// DUAL:   two B matrices (gate+up), SiLU fused, bf16 act store
// EXPERT: blockIdx.z = expert, M = counts[e]
// ABF16:  A is bf16 activation buffer (else fp32, converted while staging)
// ATOMIC: scaled atomicAdd(out[token])
// ---------------------------------------------------------------------------
template<int DUAL, int EXPERT, int ABF16, int ATOMIC, int BM>
__global__ __launch_bounds__(512) void gemm_k(
    const void* __restrict__ Av, const float* __restrict__ B1g,
    const float* __restrict__ B2g, void* __restrict__ outv,
    const int* __restrict__ counts, const int* __restrict__ offsets,
    const int* __restrict__ ltok, const float* __restrict__ lw,
    int M, int N, int K)
{
    constexpr int FM = BM / 64;    // A frags per wave
    constexpr int WR = BM / 4;     // rows per M-wave stripe
    constexpr int NI = BM / 128;   // A staging iterations

    const int e = blockIdx.z;
    int Mloc = EXPERT ? counts[e] : M;
    const int row0 = blockIdx.x * BM;
    if (row0 >= Mloc) return;
    const int col0 = blockIdx.y * 64;

    const float* B1 = B1g;
    const float* B2 = B2g;
    if (EXPERT) {
        size_t eo = (size_t)e * K * N;
        B1 += eo;
        if (DUAL) B2 += eo;
    }

    __shared__ unsigned short lA[2][BM][40];
    __shared__ unsigned short lB[2][DUAL + 1][64][40];

    const int tid = threadIdx.x;
    const int lane = tid & 63;
    const int wv = tid >> 6;
    const int wm = wv >> 1;        // 0..3
    const int wn = wv & 1;         // 0..1

    // ---- A staging pointers: row = i*128 + (tid>>2), k-chunk = (tid&3)*8 ----
    const float* arf[NI];
    const unsigned short* arb[NI];
    if (ABF16) {
        const unsigned short* A = (const unsigned short*)Av;
        const int rb = EXPERT ? offsets[e] : 0;
        #pragma unroll
        for (int i = 0; i < NI; ++i) {
            int rr = row0 + i * 128 + (tid >> 2);
            if (rr >= Mloc) rr = Mloc - 1;
            arb[i] = A + (size_t)(rb + rr) * K + (tid & 3) * 8;
        }
    } else {
        const float* A = (const float*)Av;
        #pragma unroll
        for (int i = 0; i < NI; ++i) {
            int rr = row0 + i * 128 + (tid >> 2);
            if (rr >= Mloc) rr = Mloc - 1;
            int grow = EXPERT ? ltok[e * T_TOK + rr] : rr;
            arf[i] = A + (size_t)grow * K + (tid & 3) * 8;
        }
    }

    // ---- B staging: 256 threads per matrix; 4k x 4n micro-tile transpose ----
    const int bmat = DUAL ? (tid >> 8) : 0;
    const bool doB = DUAL ? true : (tid < 256);
    const int t8 = tid & 255;
    const int nq = t8 & 15;        // n group of 4
    const int kq = t8 >> 4;        // k pair index 0..15 (covers 32 k)
    const float* bp = (bmat ? B2 : B1) + (size_t)(2 * kq) * N + col0 + nq * 4;

    f32x4 acc1[FM][2], acc2[FM][2];
    #pragma unroll
    for (int a = 0; a < FM; ++a)
        #pragma unroll
        for (int b = 0; b < 2; ++b) {
            acc1[a][b] = f32x4{0.f, 0.f, 0.f, 0.f};
            acc2[a][b] = f32x4{0.f, 0.f, 0.f, 0.f};
        }

    f32x4 pa[NI * 2];
    u16x8 pab[NI];
    f32x4 pb0, pb1;

    auto loadT = [&](int k0) {
        if (ABF16) {
            #pragma unroll
            for (int i = 0; i < NI; ++i) pab[i] = *(const u16x8*)(arb[i] + k0);
        } else {
            #pragma unroll
            for (int i = 0; i < NI; ++i) {
                pa[2 * i]     = *(const f32x4*)(arf[i] + k0);
                pa[2 * i + 1] = *(const f32x4*)(arf[i] + k0 + 4);
            }
        }
        if (doB) {
            pb0 = *(const f32x4*)(bp + (size_t)k0 * N);
            pb1 = *(const f32x4*)(bp + (size_t)(k0 + 1) * N);
        }
    };

    auto storeT = [&](int p) {
        if (ABF16) {
            #pragma unroll
            for (int i = 0; i < NI; ++i)
                *(u16x8*)&lA[p][i * 128 + (tid >> 2)][(tid & 3) * 8] = pab[i];
        } else {
            #pragma unroll
            for (int i = 0; i < NI; ++i) {
                u16x8 h = { f2bf(pa[2*i][0]), f2bf(pa[2*i][1]),
                            f2bf(pa[2*i][2]), f2bf(pa[2*i][3]),
                            f2bf(pa[2*i+1][0]), f2bf(pa[2*i+1][1]),
                            f2bf(pa[2*i+1][2]), f2bf(pa[2*i+1][3]) };
                *(u16x8*)&lA[p][i * 128 + (tid >> 2)][(tid & 3) * 8] = h;
            }
        }
        if (doB) {
            #pragma unroll
            for (int j = 0; j < 4; ++j) {
                u16x2 h = { f2bf(pb0[j]), f2bf(pb1[j]) };
                *(u16x2*)&lB[p][bmat][nq * 4 + j][kq * 2] = h;
            }
        }
    };

    const int nk = K >> 5;
    loadT(0);
    storeT(0);
    __syncthreads();

    for (int kt = 0; kt < nk; ++kt) {
        const int p = kt & 1;
        if (kt + 1 < nk) loadT((kt + 1) << 5);   // next tile in flight
        // ---- compute from buf p ----
        {
            const int koff = (lane >> 4) * 8;
            s16x8 af[FM], b1f[2], b2f[2];
            #pragma unroll
            for (int fm = 0; fm < FM; ++fm)
                af[fm] = *(const s16x8*)&lA[p][wm * WR + fm * 16 + (lane & 15)][koff];
            #pragma unroll
            for (int fn = 0; fn < 2; ++fn) {
                b1f[fn] = *(const s16x8*)&lB[p][0][wn * 32 + fn * 16 + (lane & 15)][koff];
                if (DUAL)
                    b2f[fn] = *(const s16x8*)&lB[p][1][wn * 32 + fn * 16 + (lane & 15)][koff];
            }
            #pragma unroll
            for (int fm = 0; fm < FM; ++fm)
                #pragma unroll
                for (int fn = 0; fn < 2; ++fn) {
                    acc1[fm][fn] = __builtin_amdgcn_mfma_f32_16x16x32_bf16(
                        af[fm], b1f[fn], acc1[fm][fn], 0, 0, 0);
                    if (DUAL)
                        acc2[fm][fn] = __builtin_amdgcn_mfma_f32_16x16x32_bf16(
                            af[fm], b2f[fn], acc2[fm][fn], 0, 0, 0);
                }
        }
        if (kt + 1 < nk) {
            storeT(p ^ 1);        // vmcnt wait lands here, after compute
            __syncthreads();
        }
    }

    // ---- epilogue ----
    const int fr = (lane >> 4) << 2;
    const int fc = lane & 15;
    if (DUAL) {
        unsigned short* outp = (unsigned short*)outv;
        const int rb = EXPERT ? offsets[e] : 0;
        #pragma unroll
        for (int fm = 0; fm < FM; ++fm)
            #pragma unroll
            for (int fn = 0; fn < 2; ++fn)
                #pragma unroll
                for (int j = 0; j < 4; ++j) {
                    int r = wm * WR + fm * 16 + fr + j;
                    if (row0 + r < Mloc) {
                        int cc = col0 + wn * 32 + fn * 16 + fc;
                        float gv = acc1[fm][fn][j];
                        float uv = acc2[fm][fn][j];
                        float a = gv / (1.f + expf(-gv)) * uv;
                        outp[(size_t)(rb + row0 + r) * N + cc] = f2bf(a);
                    }
                }
    } else if (ATOMIC) {
        float* outp = (float*)outv;
        #pragma unroll
        for (int fm = 0; fm < FM; ++fm)
            #pragma unroll
            for (int fn = 0; fn < 2; ++fn)
                #pragma unroll
                for (int j = 0; j < 4; ++j) {
                    int r = wm * WR + fm * 16 + fr + j;
                    if (row0 + r < Mloc) {
                        int tok = ltok[e * T_TOK + row0 + r];
                        float wr = lw[e * T_TOK + row0 + r];
                        int cc = col0 + wn * 32 + fn * 16 + fc;
                        atomicAdd(outp + (size_t)tok * N + cc, acc1[fm][fn][j] * wr);
                    }
                }
    } else {
        float* outp = (float*)outv;
        #pragma unroll
        for (int fm = 0; fm < FM; ++fm)
            #pragma unroll
            for (int fn = 0; fn < 2; ++fn)
                #pragma unroll
                for (int j = 0; j < 4; ++j) {
                    int r = wm * WR + fm * 16 + fr + j;
                    if (row0 + r < Mloc) {
                        int cc = col0 + wn * 32 + fn * 16 + fc;
                        outp[(size_t)(row0 + r) * N + cc] = acc1[fm][fn][j];
                    }
                }
    }
}

// ---------------------------------------------------------------------------
extern "C" void kernel_launch(void* const* d_in, const int* in_sizes, int n_in,
                              void* d_out, int out_size, void* d_ws, size_t ws_size,
                              hipStream_t stream) {
    const float* x       = (const float*)d_in[0];
    const float* gate_w  = (const float*)d_in[1];
    const float* bias    = (const float*)d_in[2];
    const float* w_gate  = (const float*)d_in[3];
    const float* w_up    = (const float*)d_in[4];
    const float* w_down  = (const float*)d_in[5];
    const float* sw_gate = (const float*)d_in[6];
    const float* sw_up   = (const float*)d_in[7];
    const float* sw_down = (const float*)d_in[8];
    float* out = (float*)d_out;

    char* ws = (char*)d_ws;
    int*   topk_idx = (int*)ws;                                   // 32 KB
    float* topk_w   = (float*)(ws + 32768);                       // 32 KB
    int*   counts   = (int*)(ws + 65536);                         // 128 B
    int*   offsets  = (int*)(ws + 65536 + 128);                   // 128 B
    int*   ltok     = (int*)(ws + 65536 + 256);                   // 128 KB
    float* lw       = (float*)(ws + 65536 + 256 + 131072);        // 128 KB
    unsigned short* act_s = (unsigned short*)(ws + 65536 + 256 + 262144);  // 4 MB
    unsigned short* act_r = act_s + (size_t)T_TOK * IS_DIM;               // 16 MB

    route_k<<<T_TOK, 64, 0, stream>>>(x, gate_w, bias, topk_idx, topk_w);
    build_k<<<E_NUM, 64, 0, stream>>>(topk_idx, topk_w, ltok, lw, counts);
    prefix_k<<<1, 64, 0, stream>>>(counts, offsets);

    // shared gate/up -> act_s (bf16): BM=128, 256 blocks
    gemm_k<1,0,0,0,128><<<dim3(8, 32, 1), 512, 0, stream>>>(
        x, sw_gate, sw_up, act_s, nullptr, nullptr, nullptr, nullptr,
        T_TOK, IS_DIM, H_DIM);
    // routed gate/up -> act_r (bf16): BM=256, B panels read once
    gemm_k<1,1,0,0,256><<<dim3(4, 16, 32), 512, 0, stream>>>(
        x, w_gate, w_up, act_r, counts, offsets, ltok, lw,
        T_TOK, I_DIM, H_DIM);
    // shared down -> out (plain store, initializes out): BM=128
    gemm_k<0,0,1,0,128><<<dim3(8, 32, 1), 512, 0, stream>>>(
        act_s, sw_down, nullptr, out, nullptr, nullptr, nullptr, nullptr,
        T_TOK, H_DIM, IS_DIM);
    // routed down -> out (scaled atomicAdd): BM=256
    gemm_k<0,1,1,1,256><<<dim3(4, 32, 32), 512, 0, stream>>>(
        act_r, w_down, nullptr, out, counts, offsets, ltok, lw,
        T_TOK, H_DIM, I_DIM);
}